// Round 1
// 515.023 us; speedup vs baseline: 1.3255x; 1.3255x over previous
//
#include <hip/hip_runtime.h>

typedef unsigned short u16;
typedef __attribute__((ext_vector_type(8))) short bf16x8;
typedef __attribute__((ext_vector_type(4))) float f32x4;

__device__ inline float bf2f(u16 h) {
    union { unsigned u; float f; } v; v.u = ((unsigned)h) << 16; return v.f;
}
__device__ inline u16 f2bf(float f) {
    union { float f; unsigned u; } v; v.f = f;
    unsigned r = v.u + 0x7fffu + ((v.u >> 16) & 1u);
    return (u16)(r >> 16);
}

__device__ inline void gl_lds16(const u16* g, u16* l) {
    __builtin_amdgcn_global_load_lds(
        (const __attribute__((address_space(1))) void*)g,
        (__attribute__((address_space(3))) void*)l, 16, 0, 0);
}

// ---------------------------------------------------------------------------
// f32 -> bf16 elementwise convert, up to 4 arrays per launch (blockIdx.y
// selects the array). n* counted in float4 units (elems/4). Round-to-nearest-
// even, identical to the f2bf the GEMM staging used to apply.
// ---------------------------------------------------------------------------
__global__ __launch_bounds__(256) void cvt_bf16_k(
    const float* __restrict__ s0, u16* __restrict__ d0, long long n0,
    const float* __restrict__ s1, u16* __restrict__ d1, long long n1,
    const float* __restrict__ s2, u16* __restrict__ d2, long long n2,
    const float* __restrict__ s3, u16* __restrict__ d3, long long n3)
{
    int y = blockIdx.y;
    const float* s = (y == 0) ? s0 : (y == 1) ? s1 : (y == 2) ? s2 : s3;
    u16* d         = (y == 0) ? d0 : (y == 1) ? d1 : (y == 2) ? d2 : d3;
    long long n    = (y == 0) ? n0 : (y == 1) ? n1 : (y == 2) ? n2 : n3;
    for (long long i = (long long)blockIdx.x * 256 + threadIdx.x; i < n;
         i += (long long)gridDim.x * 256) {
        float4 v = ((const float4*)s)[i];
        union { u16 h[4]; unsigned long long u; } p;
        p.h[0] = f2bf(v.x); p.h[1] = f2bf(v.y);
        p.h[2] = f2bf(v.z); p.h[3] = f2bf(v.w);
        ((unsigned long long*)d)[i] = p.u;
    }
}

// ---------------------------------------------------------------------------
// GEMM: C[M,N] = (A[M,K] @ Bt[N,K]^T) * scale + bias[N]
// A, Bt bf16 (async global_load_lds 16B). COUTF32: C written f32, else bf16.
// 128x128 tile, BK=32, 256 thr (4 waves 2x2 of 64x64), 16x16x32 bf16 MFMA.
// ---------------------------------------------------------------------------
#define BM 128
#define BN 128
#define BK 32

template <int COUTF32>
__global__ __launch_bounds__(256, 2) void gemm_bt(
    const u16* __restrict__ A, const u16* __restrict__ Bt,
    const float* __restrict__ bias, void* __restrict__ Cv,
    int M, int N, int K, float scale,
    long long sAb, long long sBb, long long sCb)
{
    __shared__ u16 As[BM * BK];
    __shared__ u16 Bs[BN * BK];

    int b = blockIdx.z;
    int bm0 = blockIdx.x * BM;
    int bn0 = blockIdx.y * BN;
    int tid = threadIdx.x;
    int w = tid >> 6, l = tid & 63;
    int wm = (w >> 1) * 64, wn = (w & 1) * 64;
    int lane15 = l & 15, quad = l >> 4;
    int lr = l >> 2;            // row within 16-row staging chunk
    int lc = (l & 3) * 8;       // elem offset within 32-elem row

    f32x4 acc[4][4];
#pragma unroll
    for (int i = 0; i < 4; i++)
#pragma unroll
        for (int j = 0; j < 4; j++) acc[i][j] = (f32x4)(0.0f);

    const u16* Ag = A  + (long long)b * sAb + (long long)(bm0 + w * 32 + lr) * K + lc;
    const u16* Bg = Bt + (long long)b * sBb + (long long)(bn0 + w * 32 + lr) * K + lc;

    for (int k0 = 0; k0 < K; k0 += BK) {
        gl_lds16(Ag + k0,            &As[(w * 32) * BK]);
        gl_lds16(Ag + 16LL * K + k0, &As[(w * 32 + 16) * BK]);
        gl_lds16(Bg + k0,            &Bs[(w * 32) * BK]);
        gl_lds16(Bg + 16LL * K + k0, &Bs[(w * 32 + 16) * BK]);
        __syncthreads();

        bf16x8 af[4], bfr[4];
#pragma unroll
        for (int i = 0; i < 4; i++) {
            af[i]  = *(const bf16x8*)&As[(wm + i * 16 + lane15) * BK + quad * 8];
            bfr[i] = *(const bf16x8*)&Bs[(wn + i * 16 + lane15) * BK + quad * 8];
        }
#pragma unroll
        for (int i = 0; i < 4; i++)
#pragma unroll
            for (int j = 0; j < 4; j++)
                acc[i][j] = __builtin_amdgcn_mfma_f32_16x16x32_bf16(
                    af[i], bfr[j], acc[i][j], 0, 0, 0);
        __syncthreads();
    }

    // C/D layout: col = lane&15, row = quad*4 + reg
    u16*   C16 = (u16*)Cv   + (long long)b * sCb;
    float* C32 = (float*)Cv + (long long)b * sCb;
#pragma unroll
    for (int j = 0; j < 4; j++) {
        int col = bn0 + wn + j * 16 + lane15;
        float bv = bias ? bias[col] : 0.0f;
#pragma unroll
        for (int i = 0; i < 4; i++) {
            int row0 = bm0 + wm + i * 16 + quad * 4;
#pragma unroll
            for (int r = 0; r < 4; r++) {
                float v = acc[i][j][r] * scale + bv;
                if (COUTF32) C32[(long long)(row0 + r) * N + col] = v;
                else         C16[(long long)(row0 + r) * N + col] = f2bf(v);
            }
        }
    }
}

// ---------------------------------------------------------------------------
__global__ __launch_bounds__(256) void transpose_k(const u16* __restrict__ V,
                                                   u16* __restrict__ Vt)
{
    __shared__ u16 tile[64][65];
    int b = blockIdx.z;
    int s0 = blockIdx.x * 64, d0 = blockIdx.y * 64;
    const u16* Vb = V + (long long)b * 2048 * 1024;
    u16* Vtb = Vt + (long long)b * 1024 * 2048;
    int tx = threadIdx.x & 63, ty = threadIdx.x >> 6;
#pragma unroll
    for (int i = ty; i < 64; i += 4)
        tile[i][tx] = Vb[(long long)(s0 + i) * 1024 + d0 + tx];
    __syncthreads();
#pragma unroll
    for (int i = ty; i < 64; i += 4)
        Vtb[(long long)(d0 + i) * 2048 + s0 + tx] = tile[tx][i];
}

// ---------------------------------------------------------------------------
// Row softmax in-place: 8192 rows of 2048 bf16
// ---------------------------------------------------------------------------
__global__ __launch_bounds__(256) void softmax_k(u16* __restrict__ Sc)
{
    long long row = blockIdx.x;
    u16* s = Sc + row * 2048;
    int t = threadIdx.x;

    uint4 raw = *(const uint4*)(s + t * 8);
    const u16* rp = (const u16*)&raw;
    float v[8];
    float mx = -3.4e38f;
#pragma unroll
    for (int j = 0; j < 8; j++) { v[j] = bf2f(rp[j]); mx = fmaxf(mx, v[j]); }
#pragma unroll
    for (int o = 32; o > 0; o >>= 1) mx = fmaxf(mx, __shfl_xor(mx, o));
    __shared__ float redm[4];
    if ((t & 63) == 0) redm[t >> 6] = mx;
    __syncthreads();
    mx = fmaxf(fmaxf(redm[0], redm[1]), fmaxf(redm[2], redm[3]));

    float sum = 0.0f;
#pragma unroll
    for (int j = 0; j < 8; j++) { v[j] = __expf(v[j] - mx); sum += v[j]; }
#pragma unroll
    for (int o = 32; o > 0; o >>= 1) sum += __shfl_xor(sum, o);
    __shared__ float reds[4];
    if ((t & 63) == 0) reds[t >> 6] = sum;
    __syncthreads();
    sum = reds[0] + reds[1] + reds[2] + reds[3];

    float inv = 1.0f / sum;
    u16 o8[8];
#pragma unroll
    for (int j = 0; j < 8; j++) o8[j] = f2bf(v[j] * inv);
    *(uint4*)(s + t * 8) = *(const uint4*)o8;
}

// ---------------------------------------------------------------------------
__global__ __launch_bounds__(256) void gate_partial(const u16* __restrict__ h,
                                                    const float* __restrict__ Wg,
                                                    float* __restrict__ part)
{
    int b = blockIdx.x, c = blockIdx.y;
    const u16* hb = h + (long long)b * 2048 * 1024 + (long long)c * 64 * 1024;
    int t = threadIdx.x;
    float acc = 0.0f;
    for (int s = 0; s < 64; s++) {
        for (int d = t; d < 1024; d += 256)
            acc += bf2f(hb[s * 1024 + d]) * Wg[d];
    }
#pragma unroll
    for (int o = 32; o > 0; o >>= 1) acc += __shfl_xor(acc, o);
    __shared__ float red[4];
    if ((t & 63) == 0) red[t >> 6] = acc;
    __syncthreads();
    if (t == 0) part[b * 32 + c] = red[0] + red[1] + red[2] + red[3];
}

__global__ void gate_final(const float* __restrict__ part,
                           const float* __restrict__ bg, float* __restrict__ outp)
{
    int t = threadIdx.x;
    if (t < 4) {
        float s = 0.0f;
        for (int c = 0; c < 32; c++) s += part[t * 32 + c];
        float v = s * (1.0f / 2048.0f) + bg[0];
        outp[t] = 1.0f / (1.0f + __expf(-v));
    }
}

// ---------------------------------------------------------------------------
// Epilogue: z = relu(mu + eps*exp(0.5*logvar)); out = LN(x+z)*gamma+beta
// All f32.
// ---------------------------------------------------------------------------
__global__ __launch_bounds__(256) void epilogue_k(
    const float* __restrict__ x, const float* __restrict__ ep,
    const float* __restrict__ mu, const float* __restrict__ lv,
    const float* __restrict__ gamma, const float* __restrict__ beta,
    float* __restrict__ out)
{
    long long base = (long long)blockIdx.x * 1024;
    int t = threadIdx.x;
    float y[4];
    float sum = 0.0f, sq = 0.0f;
#pragma unroll
    for (int j = 0; j < 4; j++) {
        int i = j * 256 + t;
        float xv = x[base + i];
        float ev = ep[base + i];
        float m  = mu[base + i];
        float sd = __expf(0.5f * lv[base + i]);
        float z  = fmaxf(m + ev * sd, 0.0f);
        float yy = xv + z;
        y[j] = yy; sum += yy; sq += yy * yy;
    }
#pragma unroll
    for (int o = 32; o > 0; o >>= 1) { sum += __shfl_xor(sum, o); sq += __shfl_xor(sq, o); }
    __shared__ float rs[4], rq[4];
    if ((t & 63) == 0) { rs[t >> 6] = sum; rq[t >> 6] = sq; }
    __syncthreads();
    sum = rs[0] + rs[1] + rs[2] + rs[3];
    sq  = rq[0] + rq[1] + rq[2] + rq[3];
    float mean = sum * (1.0f / 1024.0f);
    float var  = fmaxf(sq * (1.0f / 1024.0f) - mean * mean, 0.0f);
    float rstd = rsqrtf(var + 1e-5f);
#pragma unroll
    for (int j = 0; j < 4; j++) {
        int i = j * 256 + t;
        out[base + i] = (y[j] - mean) * rstd * gamma[i] + beta[i];
    }
}

// ---------------------------------------------------------------------------
extern "C" void kernel_launch(void* const* d_in, const int* in_sizes, int n_in,
                              void* d_out, int out_size, void* d_ws, size_t ws_size,
                              hipStream_t stream)
{
    // Inputs: float32. Outputs: float32 (out, mu, logvar, p_gate concat).
    const float* x     = (const float*)d_in[0];
    const float* ep    = (const float*)d_in[1];
    const float* Wq    = (const float*)d_in[2];
    const float* bq    = (const float*)d_in[3];
    const float* Wk    = (const float*)d_in[4];
    const float* bk    = (const float*)d_in[5];
    const float* Wv    = (const float*)d_in[6];
    const float* bv    = (const float*)d_in[7];
    const float* Wmu   = (const float*)d_in[8];
    const float* bmu   = (const float*)d_in[9];
    const float* Wlv   = (const float*)d_in[10];
    const float* blv   = (const float*)d_in[11];
    const float* Wg    = (const float*)d_in[12];
    const float* bg    = (const float*)d_in[13];
    const float* gamma = (const float*)d_in[14];
    const float* beta  = (const float*)d_in[15];
    float* out = (float*)d_out;

    const int M = 8192;       // B*S
    const int D = 1024;
    const int S = 2048;

    // f32 output regions (elements):
    float* mu_out = out + 8388608LL;   // bytes [33.55MB, 67.11MB)
    float* lv_out = out + 16777216LL;  // bytes [67.11MB, 100.66MB)
    float* pg_out = out + 25165824LL;  // 4 floats

    // Scratch overlay timeline (all inside d_out; ws holds only h = 16.78MB):
    //   out region (33.55MB):
    //     [steps 0-4]  xb (16.78MB) | Wqb | Wkb | Wvb (2MB each)  -- bf16
    //     [steps 5-7]  Sc/P (33.55MB bf16)  -- overwrites xb/W*b (dead)
    //     [steps 8-10] part (512B @ +0) + Wmub (@+4MB) + Wlvb (@+6MB)
    //     [step 11]    final out f32
    //   mu region: Q | K (bf16, steps 1-5) then mu_out f32
    //   lv region: V | Vt (bf16, steps 3-7) then lv_out f32
    u16* xb   = (u16*)out;
    u16* Wqb  = (u16*)out + 8388608LL;
    u16* Wkb  = (u16*)out + 9437184LL;
    u16* Wvb  = (u16*)out + 10485760LL;
    u16* Sc   = (u16*)out;
    u16* Q    = (u16*)mu_out;
    u16* Kb   = (u16*)mu_out + 8388608LL;
    u16* V    = (u16*)lv_out;
    u16* Vt   = (u16*)lv_out + 8388608LL;
    u16* h    = (u16*)d_ws;
    float* part = (float*)out;               // 512B, steps 8-10
    u16* Wmub = (u16*)out + 2097152LL;       // byte offset 4MB
    u16* Wlvb = (u16*)out + 3145728LL;       // byte offset 6MB

    dim3 blk(256);

    // 0. Convert x, Wq, Wk, Wv to bf16 (round-to-nearest-even, same as the
    //    old in-GEMM f2bf staging -> bit-identical numerics).
    cvt_bf16_k<<<dim3(2048, 4), blk, 0, stream>>>(
        x,  xb,  2097152LL,     // 8388608 elems / 4
        Wq, Wqb, 262144LL,
        Wk, Wkb, 262144LL,
        Wv, Wvb, 262144LL);

    // 1-3. Q = x@Wq^T+bq, K = x@Wk^T+bk, V = x@Wv^T+bv  (bf16 fast path)
    gemm_bt<0><<<dim3(64, 8, 1), blk, 0, stream>>>(xb, Wqb, bq, Q,  M, D, D, 1.0f, 0, 0, 0);
    gemm_bt<0><<<dim3(64, 8, 1), blk, 0, stream>>>(xb, Wkb, bk, Kb, M, D, D, 1.0f, 0, 0, 0);
    gemm_bt<0><<<dim3(64, 8, 1), blk, 0, stream>>>(xb, Wvb, bv, V,  M, D, D, 1.0f, 0, 0, 0);

    // 4. V^T per batch
    transpose_k<<<dim3(32, 16, 4), blk, 0, stream>>>(V, Vt);

    // 5. scores = Q @ K^T / 48 per batch -> Sc (overwrites xb/W*b, now dead)
    gemm_bt<0><<<dim3(16, 16, 4), blk, 0, stream>>>(Q, Kb, nullptr, Sc, S, S, D,
        1.0f / 48.0f, (long long)S * D, (long long)S * D, (long long)S * S);

    // 6. softmax in place
    softmax_k<<<dim3(8192), blk, 0, stream>>>(Sc);

    // 7. h = P @ V (via Vt) per batch -> ws (bf16); consumes Sc
    gemm_bt<0><<<dim3(16, 8, 4), blk, 0, stream>>>(Sc, Vt, nullptr, h, S, D, S,
        1.0f, (long long)S * S, (long long)D * S, (long long)S * D);

    // 8. Convert Wmu, Wlv to bf16 into the now-dead Sc region.
    cvt_bf16_k<<<dim3(512, 2), blk, 0, stream>>>(
        Wmu, Wmub, 262144LL,
        Wlv, Wlvb, 262144LL,
        nullptr, nullptr, 0LL,
        nullptr, nullptr, 0LL);

    // 9-10. mu, logvar -> f32 outputs (Q/K dead; V/Vt dead)
    gemm_bt<1><<<dim3(64, 8, 1), blk, 0, stream>>>(h, Wmub, bmu, (void*)mu_out, M, D, D, 1.0f, 0, 0, 0);
    gemm_bt<1><<<dim3(64, 8, 1), blk, 0, stream>>>(h, Wlvb, blv, (void*)lv_out, M, D, D, 1.0f, 0, 0, 0);

    // 11. gate -> f32 p_gate
    gate_partial<<<dim3(4, 32), blk, 0, stream>>>(h, Wg, part);
    gate_final<<<dim3(1), dim3(64), 0, stream>>>(part, bg, pg_out);

    // 12. out = LN(x + relu(mu + eps*exp(0.5*logvar))) -> f32 (overwrites scratch)
    epilogue_k<<<dim3(8192), blk, 0, stream>>>(x, ep, mu_out, lv_out, gamma, beta, out);
}

// Round 2
// 457.672 us; speedup vs baseline: 1.4916x; 1.1253x over previous
//
#include <hip/hip_runtime.h>

typedef unsigned short u16;
typedef __attribute__((ext_vector_type(8))) short bf16x8;
typedef __attribute__((ext_vector_type(4))) float f32x4;

__device__ inline float bf2f(u16 h) {
    union { unsigned u; float f; } v; v.u = ((unsigned)h) << 16; return v.f;
}
__device__ inline u16 f2bf(float f) {
    union { float f; unsigned u; } v; v.f = f;
    unsigned r = v.u + 0x7fffu + ((v.u >> 16) & 1u);
    return (u16)(r >> 16);
}

__device__ inline void gl_lds16(const u16* g, u16* l) {
    __builtin_amdgcn_global_load_lds(
        (const __attribute__((address_space(1))) void*)g,
        (__attribute__((address_space(3))) void*)l, 16, 0, 0);
}

// ---------------------------------------------------------------------------
// f32 -> bf16 elementwise convert, up to 4 arrays per launch (blockIdx.y
// selects the array). n* counted in float4 units (elems/4).
// ---------------------------------------------------------------------------
__global__ __launch_bounds__(256) void cvt_bf16_k(
    const float* __restrict__ s0, u16* __restrict__ d0, long long n0,
    const float* __restrict__ s1, u16* __restrict__ d1, long long n1,
    const float* __restrict__ s2, u16* __restrict__ d2, long long n2,
    const float* __restrict__ s3, u16* __restrict__ d3, long long n3)
{
    int y = blockIdx.y;
    const float* s = (y == 0) ? s0 : (y == 1) ? s1 : (y == 2) ? s2 : s3;
    u16* d         = (y == 0) ? d0 : (y == 1) ? d1 : (y == 2) ? d2 : d3;
    long long n    = (y == 0) ? n0 : (y == 1) ? n1 : (y == 2) ? n2 : n3;
    for (long long i = (long long)blockIdx.x * 256 + threadIdx.x; i < n;
         i += (long long)gridDim.x * 256) {
        float4 v = ((const float4*)s)[i];
        union { u16 h[4]; unsigned long long u; } p;
        p.h[0] = f2bf(v.x); p.h[1] = f2bf(v.y);
        p.h[2] = f2bf(v.z); p.h[3] = f2bf(v.w);
        ((unsigned long long*)d)[i] = p.u;
    }
}

// ---------------------------------------------------------------------------
// GEMM: C[M,N] = (A[M,K] @ Bt[N,K]^T) * scale + bias
// A, Bt bf16 (async global_load_lds 16B). COUTF32: C written f32, else bf16.
// BIASROW: bias indexed by output ROW (for transposed-output GEMMs),
// else by output column.
// 128x128 tile, BK=32, 256 thr (4 waves 2x2 of 64x64), 16x16x32 bf16 MFMA.
// ---------------------------------------------------------------------------
#define BM 128
#define BN 128
#define BK 32

template <int COUTF32, int BIASROW>
__global__ __launch_bounds__(256, 2) void gemm_bt(
    const u16* __restrict__ A, const u16* __restrict__ Bt,
    const float* __restrict__ bias, void* __restrict__ Cv,
    int M, int N, int K, float scale,
    long long sAb, long long sBb, long long sCb)
{
    __shared__ u16 As[BM * BK];
    __shared__ u16 Bs[BN * BK];

    int b = blockIdx.z;
    int bm0 = blockIdx.x * BM;
    int bn0 = blockIdx.y * BN;
    int tid = threadIdx.x;
    int w = tid >> 6, l = tid & 63;
    int wm = (w >> 1) * 64, wn = (w & 1) * 64;
    int lane15 = l & 15, quad = l >> 4;
    int lr = l >> 2;            // row within 16-row staging chunk
    int lc = (l & 3) * 8;       // elem offset within 32-elem row

    f32x4 acc[4][4];
#pragma unroll
    for (int i = 0; i < 4; i++)
#pragma unroll
        for (int j = 0; j < 4; j++) acc[i][j] = (f32x4)(0.0f);

    const u16* Ag = A  + (long long)b * sAb + (long long)(bm0 + w * 32 + lr) * K + lc;
    const u16* Bg = Bt + (long long)b * sBb + (long long)(bn0 + w * 32 + lr) * K + lc;

    for (int k0 = 0; k0 < K; k0 += BK) {
        gl_lds16(Ag + k0,            &As[(w * 32) * BK]);
        gl_lds16(Ag + 16LL * K + k0, &As[(w * 32 + 16) * BK]);
        gl_lds16(Bg + k0,            &Bs[(w * 32) * BK]);
        gl_lds16(Bg + 16LL * K + k0, &Bs[(w * 32 + 16) * BK]);
        __syncthreads();

        bf16x8 af[4], bfr[4];
#pragma unroll
        for (int i = 0; i < 4; i++) {
            af[i]  = *(const bf16x8*)&As[(wm + i * 16 + lane15) * BK + quad * 8];
            bfr[i] = *(const bf16x8*)&Bs[(wn + i * 16 + lane15) * BK + quad * 8];
        }
#pragma unroll
        for (int i = 0; i < 4; i++)
#pragma unroll
            for (int j = 0; j < 4; j++)
                acc[i][j] = __builtin_amdgcn_mfma_f32_16x16x32_bf16(
                    af[i], bfr[j], acc[i][j], 0, 0, 0);
        __syncthreads();
    }

    // C/D layout: col = lane&15, row = quad*4 + reg
    float rowb[4][4];
    if (BIASROW) {
#pragma unroll
        for (int i = 0; i < 4; i++)
#pragma unroll
            for (int r = 0; r < 4; r++)
                rowb[i][r] = bias[bm0 + wm + i * 16 + quad * 4 + r];
    }
    u16*   C16 = (u16*)Cv   + (long long)b * sCb;
    float* C32 = (float*)Cv + (long long)b * sCb;
#pragma unroll
    for (int j = 0; j < 4; j++) {
        int col = bn0 + wn + j * 16 + lane15;
        float bvc = (!BIASROW && bias) ? bias[col] : 0.0f;
#pragma unroll
        for (int i = 0; i < 4; i++) {
            int row0 = bm0 + wm + i * 16 + quad * 4;
#pragma unroll
            for (int r = 0; r < 4; r++) {
                float bv = BIASROW ? rowb[i][r] : bvc;
                float v = acc[i][j][r] * scale + bv;
                if (COUTF32) C32[(long long)(row0 + r) * N + col] = v;
                else         C16[(long long)(row0 + r) * N + col] = f2bf(v);
            }
        }
    }
}

// ---------------------------------------------------------------------------
// Row softmax in-place: 8192 rows of 2048 bf16
// ---------------------------------------------------------------------------
__global__ __launch_bounds__(256) void softmax_k(u16* __restrict__ Sc)
{
    long long row = blockIdx.x;
    u16* s = Sc + row * 2048;
    int t = threadIdx.x;

    uint4 raw = *(const uint4*)(s + t * 8);
    const u16* rp = (const u16*)&raw;
    float v[8];
    float mx = -3.4e38f;
#pragma unroll
    for (int j = 0; j < 8; j++) { v[j] = bf2f(rp[j]); mx = fmaxf(mx, v[j]); }
#pragma unroll
    for (int o = 32; o > 0; o >>= 1) mx = fmaxf(mx, __shfl_xor(mx, o));
    __shared__ float redm[4];
    if ((t & 63) == 0) redm[t >> 6] = mx;
    __syncthreads();
    mx = fmaxf(fmaxf(redm[0], redm[1]), fmaxf(redm[2], redm[3]));

    float sum = 0.0f;
#pragma unroll
    for (int j = 0; j < 8; j++) { v[j] = __expf(v[j] - mx); sum += v[j]; }
#pragma unroll
    for (int o = 32; o > 0; o >>= 1) sum += __shfl_xor(sum, o);
    __shared__ float reds[4];
    if ((t & 63) == 0) reds[t >> 6] = sum;
    __syncthreads();
    sum = reds[0] + reds[1] + reds[2] + reds[3];

    float inv = 1.0f / sum;
    u16 o8[8];
#pragma unroll
    for (int j = 0; j < 8; j++) o8[j] = f2bf(v[j] * inv);
    *(uint4*)(s + t * 8) = *(const uint4*)o8;
}

// ---------------------------------------------------------------------------
// Gate partial: grid (B, 128). Each block handles 16 rows of h[b] (2048x1024
// bf16) and produces one partial dot(sum_rows(h), Wg).
// Vectorized bf16x8 loads; Wg slice held in registers.
// ---------------------------------------------------------------------------
__global__ __launch_bounds__(256) void gate_partial(const u16* __restrict__ h,
                                                    const float* __restrict__ Wg,
                                                    float* __restrict__ part)
{
    int b = blockIdx.x, c = blockIdx.y;
    int t = threadIdx.x;
    int tx = t & 127;          // 128 col-groups of 8
    int ty = t >> 7;           // 2 row phases
    int d0 = tx * 8;
    const u16* hb = h + (long long)b * 2048 * 1024 + (long long)c * 16 * 1024;

    float wg[8];
#pragma unroll
    for (int j = 0; j < 8; j++) wg[j] = Wg[d0 + j];

    float acc = 0.0f;
    for (int s = ty; s < 16; s += 2) {
        bf16x8 hv = *(const bf16x8*)&hb[(long long)s * 1024 + d0];
        const u16* hp = (const u16*)&hv;
#pragma unroll
        for (int j = 0; j < 8; j++) acc += bf2f(hp[j]) * wg[j];
    }
#pragma unroll
    for (int o = 32; o > 0; o >>= 1) acc += __shfl_xor(acc, o);
    __shared__ float red[4];
    if ((t & 63) == 0) red[t >> 6] = acc;
    __syncthreads();
    if (t == 0) part[b * 128 + c] = red[0] + red[1] + red[2] + red[3];
}

__global__ void gate_final(const float* __restrict__ part,
                           const float* __restrict__ bg, float* __restrict__ outp)
{
    int t = threadIdx.x;
    if (t < 4) {
        float s = 0.0f;
        for (int c = 0; c < 128; c++) s += part[t * 128 + c];
        float v = s * (1.0f / 2048.0f) + bg[0];
        outp[t] = 1.0f / (1.0f + __expf(-v));
    }
}

// ---------------------------------------------------------------------------
// Epilogue: z = relu(mu + eps*exp(0.5*logvar)); out = LN(x+z)*gamma+beta
// All f32.
// ---------------------------------------------------------------------------
__global__ __launch_bounds__(256) void epilogue_k(
    const float* __restrict__ x, const float* __restrict__ ep,
    const float* __restrict__ mu, const float* __restrict__ lv,
    const float* __restrict__ gamma, const float* __restrict__ beta,
    float* __restrict__ out)
{
    long long base = (long long)blockIdx.x * 1024;
    int t = threadIdx.x;
    float y[4];
    float sum = 0.0f, sq = 0.0f;
#pragma unroll
    for (int j = 0; j < 4; j++) {
        int i = j * 256 + t;
        float xv = x[base + i];
        float ev = ep[base + i];
        float m  = mu[base + i];
        float sd = __expf(0.5f * lv[base + i]);
        float z  = fmaxf(m + ev * sd, 0.0f);
        float yy = xv + z;
        y[j] = yy; sum += yy; sq += yy * yy;
    }
#pragma unroll
    for (int o = 32; o > 0; o >>= 1) { sum += __shfl_xor(sum, o); sq += __shfl_xor(sq, o); }
    __shared__ float rs[4], rq[4];
    if ((t & 63) == 0) { rs[t >> 6] = sum; rq[t >> 6] = sq; }
    __syncthreads();
    sum = rs[0] + rs[1] + rs[2] + rs[3];
    sq  = rq[0] + rq[1] + rq[2] + rq[3];
    float mean = sum * (1.0f / 1024.0f);
    float var  = fmaxf(sq * (1.0f / 1024.0f) - mean * mean, 0.0f);
    float rstd = rsqrtf(var + 1e-5f);
#pragma unroll
    for (int j = 0; j < 4; j++) {
        int i = j * 256 + t;
        out[base + i] = (y[j] - mean) * rstd * gamma[i] + beta[i];
    }
}

// ---------------------------------------------------------------------------
extern "C" void kernel_launch(void* const* d_in, const int* in_sizes, int n_in,
                              void* d_out, int out_size, void* d_ws, size_t ws_size,
                              hipStream_t stream)
{
    // Inputs: float32. Outputs: float32 (out, mu, logvar, p_gate concat).
    const float* x     = (const float*)d_in[0];
    const float* ep    = (const float*)d_in[1];
    const float* Wq    = (const float*)d_in[2];
    const float* bq    = (const float*)d_in[3];
    const float* Wk    = (const float*)d_in[4];
    const float* bk    = (const float*)d_in[5];
    const float* Wv    = (const float*)d_in[6];
    const float* bv    = (const float*)d_in[7];
    const float* Wmu   = (const float*)d_in[8];
    const float* bmu   = (const float*)d_in[9];
    const float* Wlv   = (const float*)d_in[10];
    const float* blv   = (const float*)d_in[11];
    const float* Wg    = (const float*)d_in[12];
    const float* bg    = (const float*)d_in[13];
    const float* gamma = (const float*)d_in[14];
    const float* beta  = (const float*)d_in[15];
    float* out = (float*)d_out;

    const int M = 8192;       // B*S
    const int D = 1024;
    const int S = 2048;

    // f32 output regions (elements):
    float* mu_out = out + 8388608LL;   // bytes [33.55MB, 67.11MB)
    float* lv_out = out + 16777216LL;  // bytes [67.11MB, 100.66MB)
    float* pg_out = out + 25165824LL;  // 4 floats

    // Scratch overlay timeline (all inside d_out; ws holds only h = 16.78MB):
    //   out region (33.55MB):
    //     [steps 0-4]  xb (16.78MB) | Wqb | Wkb | Wvb (2MB each)  -- bf16
    //     [steps 5-7]  Sc/P (33.55MB bf16)  -- overwrites xb/W*b (dead)
    //     [steps 8-11] part (2KB @ +0) + Wmub (@+4MB) + Wlvb (@+6MB)
    //     [step 12]    final out f32
    //   mu region: Q | K (bf16) then mu_out f32
    //   lv region: (unused) | Vt (bf16) then lv_out f32
    u16* xb   = (u16*)out;
    u16* Wqb  = (u16*)out + 8388608LL;
    u16* Wkb  = (u16*)out + 9437184LL;
    u16* Wvb  = (u16*)out + 10485760LL;
    u16* Sc   = (u16*)out;
    u16* Q    = (u16*)mu_out;
    u16* Kb   = (u16*)mu_out + 8388608LL;
    u16* Vt   = (u16*)lv_out + 8388608LL;
    u16* h    = (u16*)d_ws;
    float* part = (float*)out;               // 2KB, steps 8-11
    u16* Wmub = (u16*)out + 2097152LL;       // byte offset 4MB
    u16* Wlvb = (u16*)out + 3145728LL;       // byte offset 6MB

    dim3 blk(256);

    // 0. Convert x, Wq, Wk, Wv to bf16.
    cvt_bf16_k<<<dim3(2048, 4), blk, 0, stream>>>(
        x,  xb,  2097152LL,
        Wq, Wqb, 262144LL,
        Wk, Wkb, 262144LL,
        Wv, Wvb, 262144LL);

    // 1-2. Q = x@Wq^T+bq, K = x@Wk^T+bk  (bf16 fast path)
    gemm_bt<0, 0><<<dim3(64, 8, 1), blk, 0, stream>>>(xb, Wqb, bq, Q,  M, D, D, 1.0f, 0, 0, 0);
    gemm_bt<0, 0><<<dim3(64, 8, 1), blk, 0, stream>>>(xb, Wkb, bk, Kb, M, D, D, 1.0f, 0, 0, 0);

    // 3. Vt[b] = Wv @ x[b]^T + bv (per-ROW bias) -> [D, S] per batch.
    //    Replaces V GEMM + transpose: Vt[d,s] = sum_k Wv[d,k] * x[b,s,k].
    gemm_bt<0, 1><<<dim3(8, 16, 4), blk, 0, stream>>>(Wvb, xb, bv, Vt, D, S, D,
        1.0f, 0, (long long)S * D, (long long)D * S);

    // 4. scores = Q @ K^T / 48 per batch -> Sc (overwrites xb/W*b, now dead)
    gemm_bt<0, 0><<<dim3(16, 16, 4), blk, 0, stream>>>(Q, Kb, nullptr, Sc, S, S, D,
        1.0f / 48.0f, (long long)S * D, (long long)S * D, (long long)S * S);

    // 5. softmax in place
    softmax_k<<<dim3(8192), blk, 0, stream>>>(Sc);

    // 6. h = P @ V (via Vt) per batch -> ws (bf16); consumes Sc
    gemm_bt<0, 0><<<dim3(16, 8, 4), blk, 0, stream>>>(Sc, Vt, nullptr, h, S, D, S,
        1.0f, (long long)S * S, (long long)D * S, (long long)S * D);

    // 7. Convert Wmu, Wlv to bf16 into the now-dead Sc region.
    cvt_bf16_k<<<dim3(512, 2), blk, 0, stream>>>(
        Wmu, Wmub, 262144LL,
        Wlv, Wlvb, 262144LL,
        nullptr, nullptr, 0LL,
        nullptr, nullptr, 0LL);

    // 8-9. mu, logvar -> f32 outputs
    gemm_bt<1, 0><<<dim3(64, 8, 1), blk, 0, stream>>>(h, Wmub, bmu, (void*)mu_out, M, D, D, 1.0f, 0, 0, 0);
    gemm_bt<1, 0><<<dim3(64, 8, 1), blk, 0, stream>>>(h, Wlvb, blv, (void*)lv_out, M, D, D, 1.0f, 0, 0, 0);

    // 10. gate -> f32 p_gate
    gate_partial<<<dim3(4, 128), blk, 0, stream>>>(h, Wg, part);
    gate_final<<<dim3(1), dim3(64), 0, stream>>>(part, bg, pg_out);

    // 11. out = LN(x + relu(mu + eps*exp(0.5*logvar))) -> f32
    epilogue_k<<<dim3(8192), blk, 0, stream>>>(x, ep, mu_out, lv_out, gamma, beta, out);
}